// Round 1
// baseline (115.469 us; speedup 1.0000x reference)
//
#include <hip/hip_runtime.h>

// CACE-style kernel: B[n,r,l,c] from edge rank-1 tensors segment-summed by receiver.
// Strategy: CSR bucketing (atomic counts + padded lists), then 1 block/node
// computes A in registers/LDS (never materialized in HBM) and contracts to B.

#define NN    10000
#define NE    100000
#define NRBF  8
#define NANG  20
#define NCHAN 9
#define NATOT (NRBF*NANG*NCHAN)   // 1440
#define CAP   64                  // max in-degree kept; Poisson(10) tail P(>64) ~ 1e-30
#define CHUNK 8
#define INV_CUT  (1.0f/5.5f)
#define PI_F     3.14159265358979323846f
#define RAD_NORM 0.6030226891555273f   // sqrt(2/5.5)

// lxlylz enumeration for max_l=3 (matches reference _lxlylz_list order)
__constant__ signed char cLX[NANG] = {0, 1,0,0, 2,1,1,0,0,0, 3,2,2,1,1,1,0,0,0,0};
__constant__ signed char cLY[NANG] = {0, 0,1,0, 0,1,0,2,1,0, 0,1,0,2,1,0,3,2,1,0};
__constant__ signed char cLZ[NANG] = {0, 0,0,1, 0,0,1,0,1,2, 0,0,1,0,1,2,0,1,2,3};

__global__ void zero_cnt_k(int* __restrict__ cnt) {
    int i = blockIdx.x * blockDim.x + threadIdx.x;
    if (i < NN) cnt[i] = 0;
}

__global__ void scatter_k(const int* __restrict__ ei, int* __restrict__ cnt,
                          int* __restrict__ lst) {
    int e = blockIdx.x * blockDim.x + threadIdx.x;
    if (e >= NE) return;
    int dst = ei[NE + e];                    // edge_index[1][e] = receiver
    int pos = atomicAdd(&cnt[dst], 1);
    if (pos < CAP) lst[dst * CAP + pos] = e;
}

__launch_bounds__(256, 4)
__global__ void node_k(const int* __restrict__ an, const int* __restrict__ ei,
                       const float* __restrict__ elen, const float* __restrict__ evec,
                       const float* __restrict__ W, const int* __restrict__ cnt,
                       const int* __restrict__ lst, float* __restrict__ out)
{
    __shared__ float sW[6];
    __shared__ int   s_zdst;
    __shared__ float s_ux[CHUNK], s_uy[CHUNK], s_uz[CHUNK], s_rr[CHUNK];
    __shared__ int   s_zs[CHUNK];
    __shared__ float s_rad[CHUNK][NRBF];
    __shared__ float s_ang[CHUNK][NANG];
    __shared__ float s_enc[CHUNK][NCHAN];
    __shared__ float s_pe[CHUNK][NANG*NCHAN];  // ang ⊗ enc, 180/edge
    __shared__ float s_A[NATOT];

    const int n   = blockIdx.x;
    const int tid = threadIdx.x;
    if (tid < 6)  sW[tid] = W[tid];
    if (tid == 0) s_zdst  = an[n];
    __syncthreads();

    int deg = cnt[n]; if (deg > CAP) deg = CAP;

    // Ownership: r_own = tid/32 (8 groups), each thread owns ac = g+32k, k<6
    const int r_own = tid >> 5;
    const int g     = tid & 31;
    float acc[6] = {0.f, 0.f, 0.f, 0.f, 0.f, 0.f};

    for (int base = 0; base < deg; base += CHUNK) {
        int m = min(CHUNK, deg - base);
        // phase 1: gather per-edge scalars
        if (tid < m) {
            int eid = lst[n * CAP + base + tid];
            int src = ei[eid];               // edge_index[0][eid] = sender
            float r  = elen[eid];
            float vx = evec[3*eid+0], vy = evec[3*eid+1], vz = evec[3*eid+2];
            float inv = rsqrtf(vx*vx + vy*vy + vz*vz);
            s_ux[tid] = vx*inv; s_uy[tid] = vy*inv; s_uz[tid] = vz*inv;
            s_rr[tid] = r;
            s_zs[tid] = an[src];
        }
        __syncthreads();
        // phase 2: radial(8) / ang(20) / enc(9) per edge
        {
            int total = m * (NRBF + NANG + NCHAN);
            for (int q = tid; q < total; q += 256) {
                if (q < m*NRBF) {
                    int e = q / NRBF, k = q - e*NRBF;
                    float r  = s_rr[e];
                    float u  = r * INV_CUT;
                    float u2 = u*u, u6 = u2*u2*u2;
                    float fc = (u < 1.0f) ? (1.0f - 28.0f*u6 + 48.0f*u6*u - 21.0f*u6*u2)
                                          : 0.0f;
                    float s = sinf((float)(k+1) * (PI_F*INV_CUT) * r);
                    s_rad[e][k] = RAD_NORM * s * fc / r;
                } else if (q < m*(NRBF+NANG)) {
                    int qq = q - m*NRBF;
                    int e = qq / NANG, a = qq - e*NANG;
                    float ux = s_ux[e], uy = s_uy[e], uz = s_uz[e];
                    float px[4] = {1.0f, ux, ux*ux, ux*ux*ux};
                    float py[4] = {1.0f, uy, uy*uy, uy*uy*uy};
                    float pz[4] = {1.0f, uz, uz*uz, uz*uz*uz};
                    s_ang[e][a] = px[cLX[a]] * py[cLY[a]] * pz[cLZ[a]];
                } else {
                    int qq = q - m*(NRBF+NANG);
                    int e = qq / NCHAN, c = qq - e*NCHAN;
                    int i = c / 3, j = c - i*3;        // enc[i*3+j] = emb_src[i]*emb_dst[j]
                    s_enc[e][c] = sW[s_zs[e]*3 + i] * sW[s_zdst*3 + j];
                }
            }
        }
        __syncthreads();
        // phase 2b: pe[e][a*9+c] = ang*enc
        for (int q = tid; q < m * (NANG*NCHAN); q += 256) {
            int e  = q / (NANG*NCHAN);
            int ac = q - e * (NANG*NCHAN);
            int a  = ac / NCHAN;
            s_pe[e][ac] = s_ang[e][a] * s_enc[e][ac - a*NCHAN];
        }
        __syncthreads();
        // accumulate: A[r_own][ac] += rad[e][r_own] * pe[e][ac]
        for (int e = 0; e < m; ++e) {
            float rad_e = s_rad[e][r_own];
            #pragma unroll
            for (int k = 0; k < 6; ++k) {
                int ac = g + 32*k;
                if (ac < NANG*NCHAN) acc[k] = fmaf(rad_e, s_pe[e][ac], acc[k]);
            }
        }
        __syncthreads();   // protect shared arrays before next chunk overwrites
    }

    // write A to shared (conflict-free: 32 consecutive floats per group)
    #pragma unroll
    for (int k = 0; k < 6; ++k) {
        int ac = g + 32*k;
        if (ac < NANG*NCHAN) s_A[r_own*(NANG*NCHAN) + ac] = acc[k];
    }
    __syncthreads();

    // B[n, r, l, c]: l=0 linear, l=1..3 multinomial-weighted sum of squares
    for (int o = tid; o < NRBF*4*NCHAN; o += 256) {
        int r = o / 36, rem = o - r*36, l = rem / 9, c = rem - (rem/9)*9;
        const float* Ar = &s_A[r*(NANG*NCHAN) + c];   // stride 9 per a
        float val;
        if (l == 0) {
            val = Ar[0];
        } else if (l == 1) {   // a=1..3, pref {1,1,1}
            float v1 = Ar[9], v2 = Ar[18], v3 = Ar[27];
            val = v1*v1 + v2*v2 + v3*v3;
        } else if (l == 2) {   // a=4..9, pref {1,2,2,1,2,1}
            float v0=Ar[36], v1=Ar[45], v2=Ar[54], v3=Ar[63], v4=Ar[72], v5=Ar[81];
            val = v0*v0 + 2.0f*(v1*v1 + v2*v2 + v4*v4) + v3*v3 + v5*v5;
        } else {               // a=10..19, pref {1,3,3,3,6,3,1,3,3,1}
            float w0=Ar[90],  w1=Ar[99],  w2=Ar[108], w3=Ar[117], w4=Ar[126];
            float w5=Ar[135], w6=Ar[144], w7=Ar[153], w8=Ar[162], w9=Ar[171];
            val = w0*w0 + w6*w6 + w9*w9
                + 3.0f*(w1*w1 + w2*w2 + w3*w3 + w5*w5 + w7*w7 + w8*w8)
                + 6.0f*w4*w4;
        }
        out[n*(NRBF*4*NCHAN) + o] = val;
    }
}

extern "C" void kernel_launch(void* const* d_in, const int* in_sizes, int n_in,
                              void* d_out, int out_size, void* d_ws, size_t ws_size,
                              hipStream_t stream) {
    // inputs: 0 positions (unused), 1 atomic_numbers, 2 edge_index,
    //         3 edge_lengths, 4 edge_vectors, 5 W_embed
    const int*   an   = (const int*)d_in[1];
    const int*   ei   = (const int*)d_in[2];
    const float* elen = (const float*)d_in[3];
    const float* evec = (const float*)d_in[4];
    const float* W    = (const float*)d_in[5];
    float* out = (float*)d_out;

    int* cnt = (int*)d_ws;           // NN ints
    int* lst = cnt + NN;             // NN*CAP ints (~2.56 MB)

    zero_cnt_k<<<(NN + 255)/256, 256, 0, stream>>>(cnt);
    scatter_k<<<(NE + 255)/256, 256, 0, stream>>>(ei, cnt, lst);
    node_k<<<NN, 256, 0, stream>>>(an, ei, elen, evec, W, cnt, lst, out);
}

// Round 2
// 108.699 us; speedup vs baseline: 1.0623x; 1.0623x over previous
//
#include <hip/hip_runtime.h>

// CACE edge-basis -> segment-sum -> invariant contraction.
// CSR bucketing (atomics), then 1 block/node: A kept in registers/LDS only.
// v2: constant-index basis compute on gather threads, c-padded pe layout,
//     r-blocked accumulate (float4 rad broadcast + float2 pe), 3 syncs/node.

#define NN    10000
#define NE    100000
#define NRBF  8
#define NANG  20
#define NCHAN 9
#define CAP   64           // Poisson(10) tail beyond 64 ~ 1e-30
#define CHUNK 16           // one chunk covers ~97% of nodes
#define BROW  40           // basis row: rad[0..8) ang[8..28) enc[28..37), pad 40
#define PROW  240          // pe row: 20 a * 12 (c padded 9->12, pads stay 0)
#define INV_CUT  (1.0f/5.5f)
#define PI_F     3.14159265358979323846f
#define RAD_NORM 0.6030226891555273f   // sqrt(2/5.5)

__global__ void scatter_k(const int* __restrict__ ei, int* __restrict__ cnt,
                          int* __restrict__ lst) {
    int e = blockIdx.x * blockDim.x + threadIdx.x;
    if (e >= NE) return;
    int dst = ei[NE + e];                    // edge_index[1][e] = receiver
    int pos = atomicAdd(&cnt[dst], 1);
    if (pos < CAP) lst[dst * CAP + pos] = e;
}

__launch_bounds__(256, 6)
__global__ void node_k(const int* __restrict__ an, const int* __restrict__ ei,
                       const float* __restrict__ elen, const float* __restrict__ evec,
                       const float* __restrict__ W, const int* __restrict__ cnt,
                       const int* __restrict__ lst, float* __restrict__ out)
{
    __shared__ float sW[8];
    __shared__ float s_basis[CHUNK * BROW];   // 2.56 KB
    __shared__ float s_pe[CHUNK * PROW];      // 15.36 KB; reused as s_A (8*240)

    const int n   = blockIdx.x;
    const int tid = threadIdx.x;

    if (tid < 6) sW[tid] = W[tid];
    // zero pe once; pad entries (c=9..11) are never written again -> stay 0
    for (int q = tid; q < CHUNK * PROW; q += 256) s_pe[q] = 0.f;
    __syncthreads();

    int deg = cnt[n]; if (deg > CAP) deg = CAP;
    const int zd = an[n];                     // uniform

    // accumulate ownership: q = r-quad (r in [4q,4q+4)), g = pe pair (2g,2g+1)
    const int q = tid >> 7;
    const int g = tid & 127;                  // active iff g < 120 (2g < 240)
    float acc[8] = {0.f,0.f,0.f,0.f,0.f,0.f,0.f,0.f};

    // pe-build ownership: eb = edge, ab = angular index (and 16+ab for ab<4)
    const int eb = tid >> 4;
    const int ab = tid & 15;

    for (int base = 0; base < deg; base += CHUNK) {
        const int m = min(CHUNK, deg - base);

        // ---- gather + full per-edge basis (16 threads) ----
        if (tid < m) {
            const int eid = lst[n * CAP + base + tid];
            const int src = ei[eid];
            const float r  = elen[eid];
            const float vx = evec[3*eid+0], vy = evec[3*eid+1], vz = evec[3*eid+2];
            const float inv = rsqrtf(vx*vx + vy*vy + vz*vz);
            const float x = vx*inv, y = vy*inv, z = vz*inv;
            float* B = &s_basis[tid * BROW];

            // radial: sin(k*theta) by Chebyshev recurrence, k=1..8
            const float u  = r * INV_CUT;
            const float u2 = u*u, u6 = u2*u2*u2;
            const float fc = (u < 1.0f) ? (1.0f - 28.0f*u6 + 48.0f*u6*u - 21.0f*u6*u2)
                                        : 0.0f;
            const float scale = RAD_NORM * fc / r;
            float s1, c1;
            sincosf(PI_F * u, &s1, &c1);
            const float twoc = 2.0f * c1;
            float sp = 0.0f, s = s1;
            float rad[8];
            #pragma unroll
            for (int k = 0; k < 8; ++k) {
                rad[k] = scale * s;
                const float sn = twoc * s - sp;
                sp = s; s = sn;
            }
            *(float4*)&B[0] = make_float4(rad[0], rad[1], rad[2], rad[3]);
            *(float4*)&B[4] = make_float4(rad[4], rad[5], rad[6], rad[7]);

            // angular monomials, reference lxlylz order, constant indices
            const float xx = x*x, xy = x*y, xz = x*z, yy = y*y, yz = y*z, zz = z*z;
            *(float4*)&B[8]  = make_float4(1.0f, x, y, z);
            *(float4*)&B[12] = make_float4(xx, xy, xz, yy);
            *(float4*)&B[16] = make_float4(yz, zz, x*xx, y*xx);
            *(float4*)&B[20] = make_float4(z*xx, x*yy, x*yz, x*zz);
            *(float4*)&B[24] = make_float4(y*yy, z*yy, y*zz, z*zz);

            // enc[i*3+j] = W[zs][i] * W[zd][j]
            const int zs = an[src];
            const float ws0 = sW[zs*3+0], ws1 = sW[zs*3+1], ws2 = sW[zs*3+2];
            const float wd0 = sW[zd*3+0], wd1 = sW[zd*3+1], wd2 = sW[zd*3+2];
            *(float4*)&B[28] = make_float4(ws0*wd0, ws0*wd1, ws0*wd2, ws1*wd0);
            *(float4*)&B[32] = make_float4(ws1*wd1, ws1*wd2, ws2*wd0, ws2*wd1);
            B[36] = ws2*wd2;
        }
        __syncthreads();

        // ---- pe[e][a][c] = ang[e][a] * enc[e][c]  (c padded to 12) ----
        if (eb < m) {
            const float* B = &s_basis[eb * BROW];
            const float4 e0 = *(const float4*)&B[28];
            const float4 e1 = *(const float4*)&B[32];
            const float  e8 = B[36];
            {
                const float a0 = B[8 + ab];
                float* P = &s_pe[eb * PROW + ab * 12];
                *(float4*)&P[0] = make_float4(a0*e0.x, a0*e0.y, a0*e0.z, a0*e0.w);
                *(float4*)&P[4] = make_float4(a0*e1.x, a0*e1.y, a0*e1.z, a0*e1.w);
                P[8] = a0 * e8;
            }
            if (ab < 4) {
                const float a1 = B[24 + ab];           // a = 16 + ab
                float* P = &s_pe[eb * PROW + (16 + ab) * 12];
                *(float4*)&P[0] = make_float4(a1*e0.x, a1*e0.y, a1*e0.z, a1*e0.w);
                *(float4*)&P[4] = make_float4(a1*e1.x, a1*e1.y, a1*e1.z, a1*e1.w);
                P[8] = a1 * e8;
            }
        }
        __syncthreads();

        // ---- accumulate: acc[r][pair] += rad[e][r] * pe[e][pair] ----
        if (g < 120) {
            for (int e = 0; e < m; ++e) {
                const float4 r4 = *(const float4*)&s_basis[e * BROW + 4*q];
                const float2 p2 = *(const float2*)&s_pe[e * PROW + 2*g];
                acc[0] = fmaf(r4.x, p2.x, acc[0]); acc[1] = fmaf(r4.x, p2.y, acc[1]);
                acc[2] = fmaf(r4.y, p2.x, acc[2]); acc[3] = fmaf(r4.y, p2.y, acc[3]);
                acc[4] = fmaf(r4.z, p2.x, acc[4]); acc[5] = fmaf(r4.z, p2.y, acc[5]);
                acc[6] = fmaf(r4.w, p2.x, acc[6]); acc[7] = fmaf(r4.w, p2.y, acc[7]);
            }
        }
        __syncthreads();   // protect s_basis/s_pe before next chunk (or s_A write)
    }

    // ---- A -> LDS (rows 0..7 of s_pe) ----
    if (g < 120) {
        #pragma unroll
        for (int rr = 0; rr < 4; ++rr) {
            *(float2*)&s_pe[(4*q + rr) * PROW + 2*g]
                = make_float2(acc[2*rr], acc[2*rr + 1]);
        }
    }
    __syncthreads();

    // ---- contraction B[n,r,l,c]; A[r][a][c] at s_pe[r*240 + a*12 + c] ----
    for (int o = tid; o < NRBF*4*NCHAN; o += 256) {
        const int r = o / 36, rem = o - r*36, l = rem / 9, c = rem - (rem/9)*9;
        const float* Ar = &s_pe[r * PROW + c];
        float val;
        if (l == 0) {
            val = Ar[0];
        } else if (l == 1) {         // a=1..3, pref {1,1,1}
            const float v1 = Ar[12], v2 = Ar[24], v3 = Ar[36];
            val = v1*v1 + v2*v2 + v3*v3;
        } else if (l == 2) {         // a=4..9, pref {1,2,2,1,2,1}
            const float v0=Ar[48], v1=Ar[60], v2=Ar[72],
                        v3=Ar[84], v4=Ar[96], v5=Ar[108];
            val = v0*v0 + 2.0f*(v1*v1 + v2*v2 + v4*v4) + v3*v3 + v5*v5;
        } else {                     // a=10..19, pref {1,3,3,3,6,3,1,3,3,1}
            const float w0=Ar[120], w1=Ar[132], w2=Ar[144], w3=Ar[156], w4=Ar[168];
            const float w5=Ar[180], w6=Ar[192], w7=Ar[204], w8=Ar[216], w9=Ar[228];
            val = w0*w0 + w6*w6 + w9*w9
                + 3.0f*(w1*w1 + w2*w2 + w3*w3 + w5*w5 + w7*w7 + w8*w8)
                + 6.0f*w4*w4;
        }
        out[n * (NRBF*4*NCHAN) + o] = val;
    }
}

extern "C" void kernel_launch(void* const* d_in, const int* in_sizes, int n_in,
                              void* d_out, int out_size, void* d_ws, size_t ws_size,
                              hipStream_t stream) {
    // inputs: 0 positions (unused), 1 atomic_numbers, 2 edge_index,
    //         3 edge_lengths, 4 edge_vectors, 5 W_embed
    const int*   an   = (const int*)d_in[1];
    const int*   ei   = (const int*)d_in[2];
    const float* elen = (const float*)d_in[3];
    const float* evec = (const float*)d_in[4];
    const float* W    = (const float*)d_in[5];
    float* out = (float*)d_out;

    int* cnt = (int*)d_ws;           // NN ints
    int* lst = cnt + NN;             // NN*CAP ints (~2.56 MB)

    hipMemsetAsync(cnt, 0, NN * sizeof(int), stream);   // graph-capturable
    scatter_k<<<(NE + 255)/256, 256, 0, stream>>>(ei, cnt, lst);
    node_k<<<NN, 256, 0, stream>>>(an, ei, elen, evec, W, cnt, lst, out);
}

// Round 3
// 105.002 us; speedup vs baseline: 1.0997x; 1.0352x over previous
//
#include <hip/hip_runtime.h>

// CACE edge-basis -> segment-sum -> invariant contraction.
// v3: (1) edge_k — fully parallel per-edge basis (rad8|ang20|enc9 -> 40-float
//     row in ws) with fused CSR scatter; (2) node_k — pure gather+FMA,
//     thread owns one (a,c) x all 8 r, no pe materialization, 2 barriers/chunk.

#define NN    10000
#define NE    100000
#define NRBF  8
#define NANG  20
#define NCHAN 9
#define CAP   64           // Poisson(10) tail beyond 64 ~ 1e-30
#define CHUNK 16
#define BROW  40           // basis row: rad[0..8) ang[8..28) enc[28..37), pad 40
#define NODE_T 192         // 3 waves; 180 active in accumulate
#define INV_CUT  (1.0f/5.5f)
#define PI_F     3.14159265358979323846f
#define RAD_NORM 0.6030226891555273f   // sqrt(2/5.5)

__launch_bounds__(256, 4)
__global__ void edge_k(const int* __restrict__ an, const int* __restrict__ ei,
                       const float* __restrict__ elen, const float* __restrict__ evec,
                       const float* __restrict__ W, int* __restrict__ cnt,
                       int* __restrict__ lst, float* __restrict__ gB)
{
    const int e = blockIdx.x * blockDim.x + threadIdx.x;
    if (e >= NE) return;

    const int src = ei[e];
    const int dst = ei[NE + e];

    // fused CSR scatter
    const int pos = atomicAdd(&cnt[dst], 1);
    if (pos < CAP) lst[dst * CAP + pos] = e;

    const float r  = elen[e];
    const float vx = evec[3*e+0], vy = evec[3*e+1], vz = evec[3*e+2];
    const float inv = rsqrtf(vx*vx + vy*vy + vz*vz);
    const float x = vx*inv, y = vy*inv, z = vz*inv;

    // radial: sin(k*pi*u) via Chebyshev recurrence, k=1..8
    const float u  = r * INV_CUT;
    const float u2 = u*u, u6 = u2*u2*u2;
    const float fc = (u < 1.0f) ? (1.0f - 28.0f*u6 + 48.0f*u6*u - 21.0f*u6*u2) : 0.0f;
    const float scale = RAD_NORM * fc / r;
    float s1, c1;
    sincosf(PI_F * u, &s1, &c1);
    const float twoc = 2.0f * c1;
    float sp = 0.0f, s = s1;
    float rad[8];
    #pragma unroll
    for (int k = 0; k < 8; ++k) {
        rad[k] = scale * s;
        const float sn = twoc * s - sp;
        sp = s; s = sn;
    }

    // angular monomials in reference lxlylz order (constant indices)
    const float xx = x*x, xy = x*y, xz = x*z, yy = y*y, yz = y*z, zz = z*z;

    // enc[i*3+j] = W[zs][i] * W[zd][j]
    const int zs = an[src], zd = an[dst];
    const float ws0 = W[zs*3+0], ws1 = W[zs*3+1], ws2 = W[zs*3+2];
    const float wd0 = W[zd*3+0], wd1 = W[zd*3+1], wd2 = W[zd*3+2];

    float4* G = (float4*)(gB + (long)e * BROW);
    G[0] = make_float4(rad[0], rad[1], rad[2], rad[3]);
    G[1] = make_float4(rad[4], rad[5], rad[6], rad[7]);
    G[2] = make_float4(1.0f, x, y, z);
    G[3] = make_float4(xx, xy, xz, yy);
    G[4] = make_float4(yz, zz, x*xx, y*xx);
    G[5] = make_float4(z*xx, x*yy, x*yz, x*zz);
    G[6] = make_float4(y*yy, z*yy, y*zz, z*zz);
    G[7] = make_float4(ws0*wd0, ws0*wd1, ws0*wd2, ws1*wd0);
    G[8] = make_float4(ws1*wd1, ws1*wd2, ws2*wd0, ws2*wd1);
    G[9] = make_float4(ws2*wd2, 0.0f, 0.0f, 0.0f);
}

__launch_bounds__(NODE_T, 8)
__global__ void node_k(const int* __restrict__ cnt, const int* __restrict__ lst,
                       const float* __restrict__ gB, float* __restrict__ out)
{
    __shared__ float sB[CHUNK * BROW];      // 2.56 KB
    __shared__ float sA[NRBF * NANG * NCHAN]; // 5.76 KB, [r*180 + a*9 + c]

    const int n   = blockIdx.x;
    const int tid = threadIdx.x;

    int deg = cnt[n]; if (deg > CAP) deg = CAP;

    const int a_own = tid / 9;              // computed once
    const int c_own = tid - a_own * 9;
    float acc[8] = {0.f,0.f,0.f,0.f,0.f,0.f,0.f,0.f};

    for (int base = 0; base < deg; base += CHUNK) {
        const int m = min(CHUNK, deg - base);

        // ---- gather basis rows into LDS (all threads, coalesced in-row) ----
        for (int i = tid; i < m * BROW; i += NODE_T) {
            const int e = i / BROW;          // 40 threads share one eid -> L1 bcast
            const int d = i - e * BROW;
            const int eid = lst[n * CAP + base + e];
            sB[i] = gB[(long)eid * BROW + d];
        }
        __syncthreads();

        // ---- accumulate: acc[r] += rad[e][r] * ang[e][a_own] * enc[e][c_own] ----
        if (tid < NANG * NCHAN) {
            for (int e = 0; e < m; ++e) {
                const float* B = &sB[e * BROW];
                const float pe = B[8 + a_own] * B[28 + c_own];
                const float4 r0 = *(const float4*)&B[0];
                const float4 r1 = *(const float4*)&B[4];
                acc[0] = fmaf(r0.x, pe, acc[0]);
                acc[1] = fmaf(r0.y, pe, acc[1]);
                acc[2] = fmaf(r0.z, pe, acc[2]);
                acc[3] = fmaf(r0.w, pe, acc[3]);
                acc[4] = fmaf(r1.x, pe, acc[4]);
                acc[5] = fmaf(r1.y, pe, acc[5]);
                acc[6] = fmaf(r1.z, pe, acc[6]);
                acc[7] = fmaf(r1.w, pe, acc[7]);
            }
        }
        __syncthreads();   // protect sB before next chunk
    }

    // ---- A -> LDS: sA[r*180 + tid], consecutive -> conflict-free ----
    if (tid < NANG * NCHAN) {
        #pragma unroll
        for (int r = 0; r < NRBF; ++r) sA[r * 180 + tid] = acc[r];
    }
    __syncthreads();

    // ---- contraction B[n,r,l,c]; A[r][a][c] at sA[r*180 + a*9 + c] ----
    for (int o = tid; o < NRBF*4*NCHAN; o += NODE_T) {
        const int r = o / 36, rem = o - r*36, l = rem / 9, c = rem - (rem/9)*9;
        const float* Ar = &sA[r * 180 + c];
        float val;
        if (l == 0) {
            val = Ar[0];
        } else if (l == 1) {         // a=1..3, pref {1,1,1}
            const float v1 = Ar[9], v2 = Ar[18], v3 = Ar[27];
            val = v1*v1 + v2*v2 + v3*v3;
        } else if (l == 2) {         // a=4..9, pref {1,2,2,1,2,1}
            const float v0=Ar[36], v1=Ar[45], v2=Ar[54],
                        v3=Ar[63], v4=Ar[72], v5=Ar[81];
            val = v0*v0 + 2.0f*(v1*v1 + v2*v2 + v4*v4) + v3*v3 + v5*v5;
        } else {                     // a=10..19, pref {1,3,3,3,6,3,1,3,3,1}
            const float w0=Ar[90],  w1=Ar[99],  w2=Ar[108], w3=Ar[117], w4=Ar[126];
            const float w5=Ar[135], w6=Ar[144], w7=Ar[153], w8=Ar[162], w9=Ar[171];
            val = w0*w0 + w6*w6 + w9*w9
                + 3.0f*(w1*w1 + w2*w2 + w3*w3 + w5*w5 + w7*w7 + w8*w8)
                + 6.0f*w4*w4;
        }
        out[n * (NRBF*4*NCHAN) + o] = val;
    }
}

extern "C" void kernel_launch(void* const* d_in, const int* in_sizes, int n_in,
                              void* d_out, int out_size, void* d_ws, size_t ws_size,
                              hipStream_t stream) {
    // inputs: 0 positions (unused), 1 atomic_numbers, 2 edge_index,
    //         3 edge_lengths, 4 edge_vectors, 5 W_embed
    const int*   an   = (const int*)d_in[1];
    const int*   ei   = (const int*)d_in[2];
    const float* elen = (const float*)d_in[3];
    const float* evec = (const float*)d_in[4];
    const float* W    = (const float*)d_in[5];
    float* out = (float*)d_out;

    // ws layout: cnt[NN] | lst[NN*CAP] | gB[NE*BROW floats]  (~18.6 MB)
    int*   cnt = (int*)d_ws;
    int*   lst = cnt + NN;
    float* gB  = (float*)(lst + (size_t)NN * CAP);

    hipMemsetAsync(cnt, 0, NN * sizeof(int), stream);
    edge_k<<<(NE + 255)/256, 256, 0, stream>>>(an, ei, elen, evec, W, cnt, lst, gB);
    node_k<<<NN, NODE_T, 0, stream>>>(cnt, lst, gB, out);
}

// Round 4
// 103.146 us; speedup vs baseline: 1.1195x; 1.0180x over previous
//
#include <hip/hip_runtime.h>

// CACE edge-basis -> segment-sum -> invariant contraction.
// v4: node_k gather restructured for minimum dependency depth:
//     lst staged to LDS once, then ONE float4 gather instruction per thread
//     (no repeated lst loads, no per-element div loop). edge_k unchanged.

#define NN    10000
#define NE    100000
#define NRBF  8
#define NANG  20
#define NCHAN 9
#define CAP   64           // Poisson(10) tail beyond 64 ~ 1e-30
#define CHUNK 16
#define BROW  40           // basis row: rad[0..8) ang[8..28) enc[28..37), pad 40
#define NODE_T 192         // 3 waves; 180 active in accumulate
#define INV_CUT  (1.0f/5.5f)
#define PI_F     3.14159265358979323846f
#define RAD_NORM 0.6030226891555273f   // sqrt(2/5.5)

__launch_bounds__(256, 4)
__global__ void edge_k(const int* __restrict__ an, const int* __restrict__ ei,
                       const float* __restrict__ elen, const float* __restrict__ evec,
                       const float* __restrict__ W, int* __restrict__ cnt,
                       int* __restrict__ lst, float* __restrict__ gB)
{
    const int e = blockIdx.x * blockDim.x + threadIdx.x;
    if (e >= NE) return;

    const int src = ei[e];
    const int dst = ei[NE + e];

    // fused CSR scatter
    const int pos = atomicAdd(&cnt[dst], 1);
    if (pos < CAP) lst[dst * CAP + pos] = e;

    const float r  = elen[e];
    const float vx = evec[3*e+0], vy = evec[3*e+1], vz = evec[3*e+2];
    const float inv = rsqrtf(vx*vx + vy*vy + vz*vz);
    const float x = vx*inv, y = vy*inv, z = vz*inv;

    // radial: sin(k*pi*u) via Chebyshev recurrence, k=1..8
    const float u  = r * INV_CUT;
    const float u2 = u*u, u6 = u2*u2*u2;
    const float fc = (u < 1.0f) ? (1.0f - 28.0f*u6 + 48.0f*u6*u - 21.0f*u6*u2) : 0.0f;
    const float scale = RAD_NORM * fc / r;
    float s1, c1;
    sincosf(PI_F * u, &s1, &c1);
    const float twoc = 2.0f * c1;
    float sp = 0.0f, s = s1;
    float rad[8];
    #pragma unroll
    for (int k = 0; k < 8; ++k) {
        rad[k] = scale * s;
        const float sn = twoc * s - sp;
        sp = s; s = sn;
    }

    // angular monomials in reference lxlylz order (constant indices)
    const float xx = x*x, xy = x*y, xz = x*z, yy = y*y, yz = y*z, zz = z*z;

    // enc[i*3+j] = W[zs][i] * W[zd][j]
    const int zs = an[src], zd = an[dst];
    const float ws0 = W[zs*3+0], ws1 = W[zs*3+1], ws2 = W[zs*3+2];
    const float wd0 = W[zd*3+0], wd1 = W[zd*3+1], wd2 = W[zd*3+2];

    float4* G = (float4*)(gB + (long)e * BROW);
    G[0] = make_float4(rad[0], rad[1], rad[2], rad[3]);
    G[1] = make_float4(rad[4], rad[5], rad[6], rad[7]);
    G[2] = make_float4(1.0f, x, y, z);
    G[3] = make_float4(xx, xy, xz, yy);
    G[4] = make_float4(yz, zz, x*xx, y*xx);
    G[5] = make_float4(z*xx, x*yy, x*yz, x*zz);
    G[6] = make_float4(y*yy, z*yy, y*zz, z*zz);
    G[7] = make_float4(ws0*wd0, ws0*wd1, ws0*wd2, ws1*wd0);
    G[8] = make_float4(ws1*wd1, ws1*wd2, ws2*wd0, ws2*wd1);
    G[9] = make_float4(ws2*wd2, 0.0f, 0.0f, 0.0f);
}

__launch_bounds__(NODE_T, 8)
__global__ void node_k(const int* __restrict__ cnt, const int* __restrict__ lst,
                       const float* __restrict__ gB, float* __restrict__ out)
{
    __shared__ int   sLst[CHUNK];
    __shared__ float sB[CHUNK * BROW];        // 2.56 KB (10 float4 per edge)
    __shared__ float sA[NRBF * NANG * NCHAN]; // 5.76 KB, [r*180 + a*9 + c]

    const int n   = blockIdx.x;
    const int tid = threadIdx.x;

    int deg = cnt[n]; if (deg > CAP) deg = CAP;   // uniform -> s_load

    const int a_own = tid / 9;
    const int c_own = tid - a_own * 9;
    float acc[8] = {0.f,0.f,0.f,0.f,0.f,0.f,0.f,0.f};

    const int e_g = tid / 10;                 // gather ownership: edge, float4-slot
    const int f_g = tid - e_g * 10;

    for (int base = 0; base < deg; base += CHUNK) {
        const int m = min(CHUNK, deg - base);

        // ---- stage edge ids (1 load) ----
        if (tid < m) sLst[tid] = lst[n * CAP + base + tid];
        __syncthreads();

        // ---- gather basis rows: ONE float4 load per thread ----
        if (e_g < m) {
            ((float4*)sB)[tid] =
                ((const float4*)gB)[(long)sLst[e_g] * (BROW/4) + f_g];
        }
        __syncthreads();

        // ---- accumulate: acc[r] += rad[e][r] * ang[e][a_own] * enc[e][c_own] ----
        if (tid < NANG * NCHAN) {
            for (int e = 0; e < m; ++e) {
                const float* B = &sB[e * BROW];
                const float pe = B[8 + a_own] * B[28 + c_own];
                const float4 r0 = *(const float4*)&B[0];
                const float4 r1 = *(const float4*)&B[4];
                acc[0] = fmaf(r0.x, pe, acc[0]);
                acc[1] = fmaf(r0.y, pe, acc[1]);
                acc[2] = fmaf(r0.z, pe, acc[2]);
                acc[3] = fmaf(r0.w, pe, acc[3]);
                acc[4] = fmaf(r1.x, pe, acc[4]);
                acc[5] = fmaf(r1.y, pe, acc[5]);
                acc[6] = fmaf(r1.z, pe, acc[6]);
                acc[7] = fmaf(r1.w, pe, acc[7]);
            }
        }
        __syncthreads();   // protect sB/sLst before next chunk
    }

    // ---- A -> LDS: sA[r*180 + tid], consecutive -> conflict-free ----
    if (tid < NANG * NCHAN) {
        #pragma unroll
        for (int r = 0; r < NRBF; ++r) sA[r * 180 + tid] = acc[r];
    }
    __syncthreads();

    // ---- contraction B[n,r,l,c]; A[r][a][c] at sA[r*180 + a*9 + c] ----
    for (int o = tid; o < NRBF*4*NCHAN; o += NODE_T) {
        const int r = o / 36, rem = o - r*36, l = rem / 9, c = rem - (rem/9)*9;
        const float* Ar = &sA[r * 180 + c];
        float val;
        if (l == 0) {
            val = Ar[0];
        } else if (l == 1) {         // a=1..3, pref {1,1,1}
            const float v1 = Ar[9], v2 = Ar[18], v3 = Ar[27];
            val = v1*v1 + v2*v2 + v3*v3;
        } else if (l == 2) {         // a=4..9, pref {1,2,2,1,2,1}
            const float v0=Ar[36], v1=Ar[45], v2=Ar[54],
                        v3=Ar[63], v4=Ar[72], v5=Ar[81];
            val = v0*v0 + 2.0f*(v1*v1 + v2*v2 + v4*v4) + v3*v3 + v5*v5;
        } else {                     // a=10..19, pref {1,3,3,3,6,3,1,3,3,1}
            const float w0=Ar[90],  w1=Ar[99],  w2=Ar[108], w3=Ar[117], w4=Ar[126];
            const float w5=Ar[135], w6=Ar[144], w7=Ar[153], w8=Ar[162], w9=Ar[171];
            val = w0*w0 + w6*w6 + w9*w9
                + 3.0f*(w1*w1 + w2*w2 + w3*w3 + w5*w5 + w7*w7 + w8*w8)
                + 6.0f*w4*w4;
        }
        out[n * (NRBF*4*NCHAN) + o] = val;
    }
}

extern "C" void kernel_launch(void* const* d_in, const int* in_sizes, int n_in,
                              void* d_out, int out_size, void* d_ws, size_t ws_size,
                              hipStream_t stream) {
    // inputs: 0 positions (unused), 1 atomic_numbers, 2 edge_index,
    //         3 edge_lengths, 4 edge_vectors, 5 W_embed
    const int*   an   = (const int*)d_in[1];
    const int*   ei   = (const int*)d_in[2];
    const float* elen = (const float*)d_in[3];
    const float* evec = (const float*)d_in[4];
    const float* W    = (const float*)d_in[5];
    float* out = (float*)d_out;

    // ws layout: cnt[NN] | lst[NN*CAP] | gB[NE*BROW floats]  (16B-aligned)
    int*   cnt = (int*)d_ws;
    int*   lst = cnt + NN;
    float* gB  = (float*)(lst + (size_t)NN * CAP);

    hipMemsetAsync(cnt, 0, NN * sizeof(int), stream);
    edge_k<<<(NE + 255)/256, 256, 0, stream>>>(an, ei, elen, evec, W, cnt, lst, gB);
    node_k<<<NN, NODE_T, 0, stream>>>(cnt, lst, gB, out);
}

// Round 5
// 95.329 us; speedup vs baseline: 1.2113x; 1.0820x over previous
//
#include <hip/hip_runtime.h>

// CACE edge-basis -> segment-sum -> invariant contraction.
// v5: NO intermediate edge-basis buffer. scatter_k builds CSR with packed
//     (eid | zs<<20). node_k = ONE WAVE PER NODE: lane e computes edge e's
//     full basis in registers (deg<=64 -> single pass), stages to a 44-float
//     padded LDS row, then lanes flip to (a,c)-pair ownership for the
//     accumulate + contraction. No cross-wave barriers, no gB round-trip.

#define NN    10000
#define NE    100000
#define NRBF  8
#define NANG  20
#define NCHAN 9
#define CAP   64           // 1 lane per edge; Poisson(10) tail beyond 64 ~ 1e-30
#define BROW  44           // LDS row: rad[0..8) ang[8..28) enc[28..37), pad 44
                           // 44*4=176B: rows 16B-aligned; stride 12 banks -> no
                           // conflicts at typical deg<=16 on the write phase
#define INV_CUT  (1.0f/5.5f)
#define PI_F     3.14159265358979323846f
#define RAD_NORM 0.6030226891555273f   // sqrt(2/5.5)

__launch_bounds__(256, 4)
__global__ void scatter_k(const int* __restrict__ an, const int* __restrict__ ei,
                          int* __restrict__ cnt, int* __restrict__ lst) {
    int e = blockIdx.x * blockDim.x + threadIdx.x;
    if (e >= NE) return;
    int src = ei[e];
    int dst = ei[NE + e];
    int zs  = an[src];                       // L2-hot 40KB table
    int pos = atomicAdd(&cnt[dst], 1);
    if (pos < CAP) lst[dst * CAP + pos] = e | (zs << 20);   // eid<2^17
}

__launch_bounds__(64, 4)
__global__ void node_k(const int* __restrict__ an, const float* __restrict__ elen,
                       const float* __restrict__ evec, const float* __restrict__ W,
                       const int* __restrict__ cnt, const int* __restrict__ lst,
                       float* __restrict__ out)
{
    __shared__ float sB[CAP * BROW];   // 11.26 KB; later aliased as sA[1440]
    float* sA = sB;

    const int n   = blockIdx.x;
    const int tid = threadIdx.x;       // 0..63, single wave

    int deg = cnt[n]; if (deg > CAP) deg = CAP;
    const int zd = an[n];              // uniform

    // W is 6 uniform floats -> registers
    const float W0=W[0], W1=W[1], W2=W[2], W3=W[3], W4=W[4], W5=W[5];
    const float wd0 = zd ? W3 : W0, wd1 = zd ? W4 : W1, wd2 = zd ? W5 : W2;

    // ---- lane e: full basis for edge e, straight into its LDS row ----
    if (tid < deg) {
        const int v   = lst[n * CAP + tid];
        const int eid = v & 0xFFFFF;
        const int zs  = v >> 20;

        const float r  = elen[eid];
        const float vx = evec[3*eid+0], vy = evec[3*eid+1], vz = evec[3*eid+2];
        const float inv = rsqrtf(vx*vx + vy*vy + vz*vz);
        const float x = vx*inv, y = vy*inv, z = vz*inv;

        // radial: sin(k*pi*u) via Chebyshev recurrence, k=1..8
        const float u  = r * INV_CUT;
        const float u2 = u*u, u6 = u2*u2*u2;
        const float fc = (u < 1.0f) ? (1.0f - 28.0f*u6 + 48.0f*u6*u - 21.0f*u6*u2)
                                    : 0.0f;
        const float scale = RAD_NORM * fc / r;
        float s1, c1;
        sincosf(PI_F * u, &s1, &c1);
        const float twoc = 2.0f * c1;
        float sp = 0.0f, s = s1;
        float rad[8];
        #pragma unroll
        for (int k = 0; k < 8; ++k) {
            rad[k] = scale * s;
            const float sn = twoc * s - sp;
            sp = s; s = sn;
        }

        const float xx = x*x, xy = x*y, xz = x*z, yy = y*y, yz = y*z, zz = z*z;
        const float ws0 = zs ? W3 : W0, ws1 = zs ? W4 : W1, ws2 = zs ? W5 : W2;

        float* B = &sB[tid * BROW];    // 16B-aligned (176B rows)
        *(float4*)&B[0]  = make_float4(rad[0], rad[1], rad[2], rad[3]);
        *(float4*)&B[4]  = make_float4(rad[4], rad[5], rad[6], rad[7]);
        *(float4*)&B[8]  = make_float4(1.0f, x, y, z);
        *(float4*)&B[12] = make_float4(xx, xy, xz, yy);
        *(float4*)&B[16] = make_float4(yz, zz, x*xx, y*xx);
        *(float4*)&B[20] = make_float4(z*xx, x*yy, x*yz, x*zz);
        *(float4*)&B[24] = make_float4(y*yy, z*yy, y*zz, z*zz);
        *(float4*)&B[28] = make_float4(ws0*wd0, ws0*wd1, ws0*wd2, ws1*wd0);
        *(float4*)&B[32] = make_float4(ws1*wd1, ws1*wd2, ws2*wd0, ws2*wd1);
        B[36] = ws2*wd2;
    }
    __syncthreads();   // single-wave barrier: ~free, forces LDS visibility

    // ---- ownership flip: lane owns pairs p = tid, tid+64, tid+128(<180) ----
    const int a0 = tid / 9,          c0 = tid - 9*a0;
    const int p1 = tid + 64,  a1 = p1 / 9, c1 = p1 - 9*a1;
    const int p2 = tid + 128, a2 = (tid < 52) ? p2 / 9 : 0,
                              c2 = (tid < 52) ? p2 - 9*(p2/9) : 0;
    float acc0[8] = {0,0,0,0,0,0,0,0};
    float acc1[8] = {0,0,0,0,0,0,0,0};
    float acc2[8] = {0,0,0,0,0,0,0,0};

    for (int e = 0; e < deg; ++e) {
        const float* B = &sB[e * BROW];
        const float4 r0 = *(const float4*)&B[0];   // wave-uniform -> broadcast
        const float4 r1 = *(const float4*)&B[4];
        const float pe0 = B[8 + a0] * B[28 + c0];  // <=29 distinct addrs -> no conflict
        const float pe1 = B[8 + a1] * B[28 + c1];
        const float pe2 = B[8 + a2] * B[28 + c2];
        acc0[0]=fmaf(r0.x,pe0,acc0[0]); acc0[1]=fmaf(r0.y,pe0,acc0[1]);
        acc0[2]=fmaf(r0.z,pe0,acc0[2]); acc0[3]=fmaf(r0.w,pe0,acc0[3]);
        acc0[4]=fmaf(r1.x,pe0,acc0[4]); acc0[5]=fmaf(r1.y,pe0,acc0[5]);
        acc0[6]=fmaf(r1.z,pe0,acc0[6]); acc0[7]=fmaf(r1.w,pe0,acc0[7]);
        acc1[0]=fmaf(r0.x,pe1,acc1[0]); acc1[1]=fmaf(r0.y,pe1,acc1[1]);
        acc1[2]=fmaf(r0.z,pe1,acc1[2]); acc1[3]=fmaf(r0.w,pe1,acc1[3]);
        acc1[4]=fmaf(r1.x,pe1,acc1[4]); acc1[5]=fmaf(r1.y,pe1,acc1[5]);
        acc1[6]=fmaf(r1.z,pe1,acc1[6]); acc1[7]=fmaf(r1.w,pe1,acc1[7]);
        acc2[0]=fmaf(r0.x,pe2,acc2[0]); acc2[1]=fmaf(r0.y,pe2,acc2[1]);
        acc2[2]=fmaf(r0.z,pe2,acc2[2]); acc2[3]=fmaf(r0.w,pe2,acc2[3]);
        acc2[4]=fmaf(r1.x,pe2,acc2[4]); acc2[5]=fmaf(r1.y,pe2,acc2[5]);
        acc2[6]=fmaf(r1.z,pe2,acc2[6]); acc2[7]=fmaf(r1.w,pe2,acc2[7]);
    }
    __syncthreads();   // all sB reads done before aliasing as sA

    // ---- A -> LDS: sA[r*180 + p] ----
    #pragma unroll
    for (int r = 0; r < NRBF; ++r) {
        sA[r*180 + tid] = acc0[r];
        sA[r*180 + p1]  = acc1[r];
        if (tid < 52) sA[r*180 + p2] = acc2[r];
    }
    __syncthreads();

    // ---- contraction B[n,r,l,c]; A[r][a][c] at sA[r*180 + a*9 + c] ----
    for (int o = tid; o < NRBF*4*NCHAN; o += 64) {
        const int r = o / 36, rem = o - r*36, l = rem / 9, c = rem - (rem/9)*9;
        const float* Ar = &sA[r * 180 + c];
        float val;
        if (l == 0) {
            val = Ar[0];
        } else if (l == 1) {         // a=1..3, pref {1,1,1}
            const float v1 = Ar[9], v2 = Ar[18], v3 = Ar[27];
            val = v1*v1 + v2*v2 + v3*v3;
        } else if (l == 2) {         // a=4..9, pref {1,2,2,1,2,1}
            const float v0=Ar[36], v1=Ar[45], v2=Ar[54],
                        v3=Ar[63], v4=Ar[72], v5=Ar[81];
            val = v0*v0 + 2.0f*(v1*v1 + v2*v2 + v4*v4) + v3*v3 + v5*v5;
        } else {                     // a=10..19, pref {1,3,3,3,6,3,1,3,3,1}
            const float w0=Ar[90],  w1=Ar[99],  w2=Ar[108], w3=Ar[117], w4=Ar[126];
            const float w5=Ar[135], w6=Ar[144], w7=Ar[153], w8=Ar[162], w9=Ar[171];
            val = w0*w0 + w6*w6 + w9*w9
                + 3.0f*(w1*w1 + w2*w2 + w3*w3 + w5*w5 + w7*w7 + w8*w8)
                + 6.0f*w4*w4;
        }
        out[n * (NRBF*4*NCHAN) + o] = val;
    }
}

extern "C" void kernel_launch(void* const* d_in, const int* in_sizes, int n_in,
                              void* d_out, int out_size, void* d_ws, size_t ws_size,
                              hipStream_t stream) {
    // inputs: 0 positions (unused), 1 atomic_numbers, 2 edge_index,
    //         3 edge_lengths, 4 edge_vectors, 5 W_embed
    const int*   an   = (const int*)d_in[1];
    const int*   ei   = (const int*)d_in[2];
    const float* elen = (const float*)d_in[3];
    const float* evec = (const float*)d_in[4];
    const float* W    = (const float*)d_in[5];
    float* out = (float*)d_out;

    // ws layout: cnt[NN] | lst[NN*CAP]  (~2.6 MB)
    int* cnt = (int*)d_ws;
    int* lst = cnt + NN;

    hipMemsetAsync(cnt, 0, NN * sizeof(int), stream);
    scatter_k<<<(NE + 255)/256, 256, 0, stream>>>(an, ei, cnt, lst);
    node_k<<<NN, 64, 0, stream>>>(an, elen, evec, W, cnt, lst, out);
}

// Round 6
// 90.380 us; speedup vs baseline: 1.2776x; 1.0548x over previous
//
#include <hip/hip_runtime.h>

// CACE edge-basis -> segment-sum -> invariant contraction.
// v6: algebraic factorization of the channel dimension. enc[i*3+j]=ws_i*wd_j
//     with wd node-uniform and ws binary (zs in {0,1}) =>
//       A[r][a][i3+j] = wd_j * (W[0,i]*S0[r,a] + W[1,i]*S1[r,a]),
//       Sz[r,a] = sum_{e: zs(e)=z} rad[e][r]*ang[e][a].
//     Accumulate shrinks 8x180 -> 2x 8x20; zs via wave-uniform __ballot mask;
//     rad read once/edge (pair layout p=a*8+r shares r across a-tiers).
//     One wave per node, LDS row 28 floats, sA aliases sB.

#define NN    10000
#define NE    100000
#define NRBF  8
#define NANG  20
#define NCHAN 9
#define CAP   64           // 1 lane per edge; Poisson(10) tail beyond 64 ~ 1e-30
#define BROW  28           // LDS row: rad[0..8) ang[8..28); 112B, 16B-aligned
#define INV_CUT  (1.0f/5.5f)
#define PI_F     3.14159265358979323846f
#define RAD_NORM 0.6030226891555273f   // sqrt(2/5.5)

__launch_bounds__(256, 4)
__global__ void scatter_k(const int* __restrict__ an, const int* __restrict__ ei,
                          int* __restrict__ cnt, int* __restrict__ lst) {
    int e = blockIdx.x * blockDim.x + threadIdx.x;
    if (e >= NE) return;
    int src = ei[e];
    int dst = ei[NE + e];
    int zs  = an[src];                       // L2-hot 40KB table
    int pos = atomicAdd(&cnt[dst], 1);
    if (pos < CAP) lst[dst * CAP + pos] = e | (zs << 20);   // eid < 2^17
}

__launch_bounds__(64, 4)
__global__ void node_k(const int* __restrict__ an, const float* __restrict__ elen,
                       const float* __restrict__ evec, const float* __restrict__ W,
                       const int* __restrict__ cnt, const int* __restrict__ lst,
                       float* __restrict__ out)
{
    __shared__ float sB[CAP * BROW];   // 7 KB; aliased as sA[1440] after barrier
    float* sA = sB;

    const int n   = blockIdx.x;
    const int tid = threadIdx.x;       // single wave

    int deg = cnt[n]; if (deg > CAP) deg = CAP;
    const int zd = an[n];              // uniform
    const float W0=W[0], W1=W[1], W2=W[2], W3=W[3], W4=W[4], W5=W[5];

    // ---- lane e: rad+ang basis for edge e -> LDS row ----
    int zsv = 0;
    if (tid < deg) {
        const int v   = lst[n * CAP + tid];
        const int eid = v & 0xFFFFF;
        zsv = v >> 20;

        const float r  = elen[eid];
        const float vx = evec[3*eid+0], vy = evec[3*eid+1], vz = evec[3*eid+2];
        const float inv = rsqrtf(vx*vx + vy*vy + vz*vz);
        const float x = vx*inv, y = vy*inv, z = vz*inv;

        // radial: sin(k*pi*u) via Chebyshev recurrence, k=1..8
        const float u  = r * INV_CUT;
        const float u2 = u*u, u6 = u2*u2*u2;
        const float fc = (u < 1.0f) ? (1.0f - 28.0f*u6 + 48.0f*u6*u - 21.0f*u6*u2)
                                    : 0.0f;
        const float scale = RAD_NORM * fc / r;
        float s1, c1;
        sincosf(PI_F * u, &s1, &c1);
        const float twoc = 2.0f * c1;
        float sp = 0.0f, s = s1;
        float rad[8];
        #pragma unroll
        for (int k = 0; k < 8; ++k) {
            rad[k] = scale * s;
            const float sn = twoc * s - sp;
            sp = s; s = sn;
        }

        const float xx = x*x, xy = x*y, xz = x*z, yy = y*y, yz = y*z, zz = z*z;
        float* B = &sB[tid * BROW];
        *(float4*)&B[0]  = make_float4(rad[0], rad[1], rad[2], rad[3]);
        *(float4*)&B[4]  = make_float4(rad[4], rad[5], rad[6], rad[7]);
        *(float4*)&B[8]  = make_float4(1.0f, x, y, z);
        *(float4*)&B[12] = make_float4(xx, xy, xz, yy);
        *(float4*)&B[16] = make_float4(yz, zz, x*xx, y*xx);
        *(float4*)&B[20] = make_float4(z*xx, x*yy, x*yz, x*zz);
        *(float4*)&B[24] = make_float4(y*yy, z*yy, y*zz, z*zz);
    }
    const unsigned long long zmask = __ballot(zsv != 0);   // wave-uniform
    __syncthreads();   // single-wave: ~free

    // ---- accumulate Sz[r,a]: pair p = a*8+r; lane owns p, p+64, p+128(<160)
    const int r0 = tid & 7;            // shared r across all 3 pairs
    const int a0 = tid >> 3;           // tiers: a0, 8+a0, 16+a0 (tid<32)
    float s00=0.f, s01=0.f, s02=0.f;   // S0 accs
    float s10=0.f, s11=0.f, s12=0.f;   // S1 accs

    for (int e = 0; e < deg; ++e) {
        const float* B = &sB[e * BROW];
        const float z1 = (float)((zmask >> e) & 1ULL);
        const float z0 = 1.0f - z1;
        const float rd = B[r0];                 // 8 distinct addrs -> multicast
        const float v0 = rd * B[8 + a0];        // 8 distinct
        const float v1 = rd * B[16 + a0];       // 8 distinct
        s00 = fmaf(v0, z0, s00); s10 = fmaf(v0, z1, s10);
        s01 = fmaf(v1, z0, s01); s11 = fmaf(v1, z1, s11);
        if (tid < 32) {
            const float v2 = rd * B[24 + a0];   // 4 distinct
            s02 = fmaf(v2, z0, s02); s12 = fmaf(v2, z1, s12);
        }
    }
    __syncthreads();   // all sB reads done before aliasing as sA

    // ---- expand A[r][a][c] = (W[0,i]*S0 + W[1,i]*S1) * wd[j], c=i*3+j ----
    const float wd0 = zd ? W3 : W0, wd1 = zd ? W4 : W1, wd2 = zd ? W5 : W2;
    {
        const float t00 = W0*s00 + W3*s10, t01 = W1*s00 + W4*s10, t02 = W2*s00 + W5*s10;
        float* Ap = &sA[r0*180 + a0*9];
        Ap[0]=t00*wd0; Ap[1]=t00*wd1; Ap[2]=t00*wd2;
        Ap[3]=t01*wd0; Ap[4]=t01*wd1; Ap[5]=t01*wd2;
        Ap[6]=t02*wd0; Ap[7]=t02*wd1; Ap[8]=t02*wd2;
    }
    {
        const float t10 = W0*s01 + W3*s11, t11 = W1*s01 + W4*s11, t12 = W2*s01 + W5*s11;
        float* Ap = &sA[r0*180 + (8 + a0)*9];
        Ap[0]=t10*wd0; Ap[1]=t10*wd1; Ap[2]=t10*wd2;
        Ap[3]=t11*wd0; Ap[4]=t11*wd1; Ap[5]=t11*wd2;
        Ap[6]=t12*wd0; Ap[7]=t12*wd1; Ap[8]=t12*wd2;
    }
    if (tid < 32) {
        const float t20 = W0*s02 + W3*s12, t21 = W1*s02 + W4*s12, t22 = W2*s02 + W5*s12;
        float* Ap = &sA[r0*180 + (16 + a0)*9];
        Ap[0]=t20*wd0; Ap[1]=t20*wd1; Ap[2]=t20*wd2;
        Ap[3]=t21*wd0; Ap[4]=t21*wd1; Ap[5]=t21*wd2;
        Ap[6]=t22*wd0; Ap[7]=t22*wd1; Ap[8]=t22*wd2;
    }
    __syncthreads();

    // ---- contraction B[n,r,l,c]; A[r][a][c] at sA[r*180 + a*9 + c] ----
    for (int o = tid; o < NRBF*4*NCHAN; o += 64) {
        const int r = o / 36, rem = o - r*36, l = rem / 9, c = rem - (rem/9)*9;
        const float* Ar = &sA[r * 180 + c];
        float val;
        if (l == 0) {
            val = Ar[0];
        } else if (l == 1) {         // a=1..3, pref {1,1,1}
            const float v1 = Ar[9], v2 = Ar[18], v3 = Ar[27];
            val = v1*v1 + v2*v2 + v3*v3;
        } else if (l == 2) {         // a=4..9, pref {1,2,2,1,2,1}
            const float v0=Ar[36], v1=Ar[45], v2=Ar[54],
                        v3=Ar[63], v4=Ar[72], v5=Ar[81];
            val = v0*v0 + 2.0f*(v1*v1 + v2*v2 + v4*v4) + v3*v3 + v5*v5;
        } else {                     // a=10..19, pref {1,3,3,3,6,3,1,3,3,1}
            const float w0=Ar[90],  w1=Ar[99],  w2=Ar[108], w3=Ar[117], w4=Ar[126];
            const float w5=Ar[135], w6=Ar[144], w7=Ar[153], w8=Ar[162], w9=Ar[171];
            val = w0*w0 + w6*w6 + w9*w9
                + 3.0f*(w1*w1 + w2*w2 + w3*w3 + w5*w5 + w7*w7 + w8*w8)
                + 6.0f*w4*w4;
        }
        out[n * (NRBF*4*NCHAN) + o] = val;
    }
}

extern "C" void kernel_launch(void* const* d_in, const int* in_sizes, int n_in,
                              void* d_out, int out_size, void* d_ws, size_t ws_size,
                              hipStream_t stream) {
    // inputs: 0 positions (unused), 1 atomic_numbers, 2 edge_index,
    //         3 edge_lengths, 4 edge_vectors, 5 W_embed
    const int*   an   = (const int*)d_in[1];
    const int*   ei   = (const int*)d_in[2];
    const float* elen = (const float*)d_in[3];
    const float* evec = (const float*)d_in[4];
    const float* W    = (const float*)d_in[5];
    float* out = (float*)d_out;

    // ws layout: cnt[NN] | lst[NN*CAP]  (~2.6 MB)
    int* cnt = (int*)d_ws;
    int* lst = cnt + NN;

    hipMemsetAsync(cnt, 0, NN * sizeof(int), stream);
    scatter_k<<<(NE + 255)/256, 256, 0, stream>>>(an, ei, cnt, lst);
    node_k<<<NN, 64, 0, stream>>>(an, elen, evec, W, cnt, lst, out);
}